// Round 5
// baseline (1459.605 us; speedup 1.0000x reference)
//
#include <hip/hip_runtime.h>
#include <stddef.h>
#include <stdint.h>

// Problem constants
#define IN_F      1024
#define SHORTLIST 4000
#define C1_LO     4000
#define C1_HI     20000
#define C2_HI     50257
#define NROWS     8192

// Workspace layout (4-byte words) -- bookkeeping region
#define WS_CNT1   0
#define WS_CNT2   1
#define WS_LOSS   2
#define WS_RL1    4
#define WS_RL2    (4 + 8192)
#define WS_SEH    (4 + 2*8192)            // sumexp_head[8192]
#define WS_SET    (WS_SEH + 8192)         // sumexp_tail[8192]
#define WS_CAP    (WS_SET + 8192)         // captured target/gather logit[8192]
#define WS_WORDS  (WS_CAP + 8192)         // ~164 KB

// bf16 scratch region (bytes)
#define WBF_OFF   (262144)                              // 256 KB aligned
#define WBF_BYTES ((size_t)C2_HI * IN_F * 2)            // 102,926,336
#define XBF_OFF   (WBF_OFF + 103219200)                 // padded/aligned
#define XBF_BYTES ((size_t)NROWS * IN_F * 2)            // 16,777,216
#define WS_NEEDED (XBF_OFF + XBF_BYTES)

typedef float          f32x4  __attribute__((ext_vector_type(4)));
typedef __bf16         bf16x8 __attribute__((ext_vector_type(8)));
typedef unsigned short us8    __attribute__((ext_vector_type(8)));
typedef unsigned short ushort_t;

__device__ __forceinline__ unsigned short f2bf(float f) {
    unsigned int u = __float_as_uint(f);
    u += 0x7fffu + ((u >> 16) & 1u);   // round-to-nearest-even
    return (unsigned short)(u >> 16);
}

__device__ __forceinline__ void gl_lds16(const void* g, void* l) {
    __builtin_amdgcn_global_load_lds(
        (const __attribute__((address_space(1))) void*)g,
        (__attribute__((address_space(3))) void*)l, 16, 0, 0);
}

// ---------------------------------------------------------------------------
// init: zero counters/accumulators, fill row lists with -1
// ---------------------------------------------------------------------------
__global__ void init_ws_k(int* __restrict__ ws) {
    int i = blockIdx.x * 256 + threadIdx.x;
    if (i < WS_WORDS) {
        int v = (i >= WS_RL1 && i < WS_RL1 + 2*8192) ? -1 : 0;
        ws[i] = v;
    }
}

// ---------------------------------------------------------------------------
// compact rows by cluster
// ---------------------------------------------------------------------------
__global__ void compact_rows_k(const int* __restrict__ target, int* __restrict__ ws) {
    int row = blockIdx.x * 256 + threadIdx.x;
    if (row >= NROWS) return;
    int tg = target[row];
    if (tg >= C1_LO) {
        if (tg < C1_HI) {
            int p = atomicAdd(&ws[WS_CNT1], 1);
            ws[WS_RL1 + p] = row;
        } else {
            int p = atomicAdd(&ws[WS_CNT2], 1);
            ws[WS_RL2 + p] = row;
        }
    }
}

// ---------------------------------------------------------------------------
// fp32 -> bf16 bulk convert (8 elems/thread)
// ---------------------------------------------------------------------------
__global__ void convert_bf16_k(const float* __restrict__ src,
                               ushort_t* __restrict__ dst, int nchunks) {
    int i = blockIdx.x * 256 + threadIdx.x;
    if (i >= nchunks) return;
    const float* p = src + (size_t)i * 8;
    f32x4 x0 = *(const f32x4*)p;
    f32x4 x1 = *(const f32x4*)(p + 4);
    us8 o;
    o[0] = f2bf(x0[0]); o[1] = f2bf(x0[1]); o[2] = f2bf(x0[2]); o[3] = f2bf(x0[3]);
    o[4] = f2bf(x1[0]); o[5] = f2bf(x1[1]); o[6] = f2bf(x1[2]); o[7] = f2bf(x1[3]);
    *(us8*)(dst + (size_t)i * 8) = o;
}

// ---------------------------------------------------------------------------
// FAST PATH: bf16 GEMM + exp-sum + target capture.
// 128x64 tile (rows x cols), BK=64, 4 waves x (4x2 of 16x16x32 MFMA).
// Smaller tile than r4's 128x128: acc 32 AGPR (was 64), LDS 26 KB (was 34),
// __launch_bounds__(256,4) caps regs at 128 -> ~4 blocks/CU co-resident to
// overlap the L2/LLC-latency-bound staging (r4 had ~1 block/CU, MfmaUtil 19%).
// GRID: blockIdx.x = ROW-strip (fast-varying) for B reuse in L2/LLC.
// ---------------------------------------------------------------------------
__launch_bounds__(256, 4)
__global__ void gemm_lse_bf16_k(const ushort_t* __restrict__ Xbf,  // [NROWS][IN_F]
                                const ushort_t* __restrict__ Wbf,  // [C2_HI][IN_F]
                                const float* __restrict__ bias,
                                const int*   __restrict__ target,
                                const int*   __restrict__ rowlist, // null => identity
                                const int*   __restrict__ cnt_ptr, // null => fixed_cnt
                                int fixed_cnt,
                                int class_base, int C,
                                float* __restrict__ sumexp,
                                float* __restrict__ capture)
{
    const int cnt = cnt_ptr ? *cnt_ptr : fixed_cnt;
    const int r0  = blockIdx.x * 128;          // row-strip fast-varying
    if (r0 >= cnt) return;
    const int c0  = blockIdx.y * 64;

    __shared__ ushort_t As[128 * 64];   // 16 KB
    __shared__ ushort_t Bs[64 * 64];    //  8 KB
    __shared__ int   orig_s[128];
    __shared__ int   tgt_s[128];
    __shared__ float bias_s[64];

    const int tid = threadIdx.x;
    if (tid < 128) {
        int idx  = r0 + tid;
        int orig = (idx < cnt) ? (rowlist ? rowlist[idx] : idx) : -1;
        orig_s[tid] = orig;
        tgt_s[tid]  = (orig >= 0) ? target[orig] : -1;
    }
    if (tid < 64) {
        int c = c0 + tid;
        bias_s[tid] = (c < C) ? bias[class_base + c] : 0.f;
    }
    __syncthreads();

    const int lane = tid & 63;
    const int wave = tid >> 6;
    const int wm = wave >> 1, wn = wave & 1;
    const int q = lane >> 4, s = lane & 15;

    // ---- staging: lane l -> row t*8 + (l>>3), LDS slot l&7,
    // data chunk = (l&7)^(l>>3) (XOR swizzle, conflict-free b128 reads)
    const int lrow  = lane >> 3;
    const int chunk = (lane & 7) ^ lrow;
    const ushort_t* aptr[4];   // A: 16 insts total, 4/wave (rows 0..127)
    const ushort_t* bptr[2];   // B:  8 insts total, 2/wave (rows 0..63)
    ushort_t* alds[4];
    ushort_t* blds[2];
#pragma unroll
    for (int i = 0; i < 4; ++i) {
        int t  = wave * 4 + i;
        int rt = t * 8 + lrow;
        int orig = orig_s[rt]; if (orig < 0) orig = 0;          // safe addr; masked later
        aptr[i] = Xbf + (size_t)orig * IN_F + chunk * 8;
        alds[i] = &As[t * 512];
    }
#pragma unroll
    for (int i = 0; i < 2; ++i) {
        int t  = wave * 2 + i;
        int rt = t * 8 + lrow;
        int c = c0 + rt; if (c >= C) c = C - 1;                  // clamp; masked later
        bptr[i] = Wbf + (size_t)(class_base + c) * IN_F + chunk * 8;
        blds[i] = &Bs[t * 512];
    }

    // ---- fragment read offsets (ushort units)
    int aoff[4], boff[2];
#pragma unroll
    for (int i = 0; i < 4; ++i) aoff[i] = (wm * 64 + i * 16 + s) * 64;
#pragma unroll
    for (int i = 0; i < 2; ++i) boff[i] = (wn * 32 + i * 16 + s) * 64;
    const int slot0 = (q ^ (s & 7)) * 8;        // k-chunk q   for ks=0
    const int slot1 = slot0 ^ (4 * 8);          // k-chunk q+4 for ks=1

    f32x4 acc[4][2];
#pragma unroll
    for (int mi = 0; mi < 4; ++mi)
#pragma unroll
        for (int ni = 0; ni < 2; ++ni) acc[mi][ni] = (f32x4)0.f;

    for (int k0 = 0; k0 < IN_F; k0 += 64) {
        __syncthreads();   // previous iteration's readers done
#pragma unroll
        for (int i = 0; i < 4; ++i) gl_lds16(aptr[i] + k0, alds[i]);
#pragma unroll
        for (int i = 0; i < 2; ++i) gl_lds16(bptr[i] + k0, blds[i]);
        __syncthreads();   // DMA drained (vmcnt(0) before barrier)

#pragma unroll
        for (int ks = 0; ks < 2; ++ks) {
            const int sl = ks ? slot1 : slot0;
            bf16x8 av[4], bv[2];
#pragma unroll
            for (int i = 0; i < 4; ++i) av[i] = *(const bf16x8*)&As[aoff[i] + sl];
#pragma unroll
            for (int i = 0; i < 2; ++i) bv[i] = *(const bf16x8*)&Bs[boff[i] + sl];
#pragma unroll
            for (int mi = 0; mi < 4; ++mi)
#pragma unroll
                for (int ni = 0; ni < 2; ++ni)
                    acc[mi][ni] = __builtin_amdgcn_mfma_f32_16x16x32_bf16(
                        av[mi], bv[ni], acc[mi][ni], 0, 0, 0);
        }
    }

    // Epilogue: C/D layout col = lane&15 (=s), row = q*4 + reg
#pragma unroll
    for (int mi = 0; mi < 4; ++mi) {
#pragma unroll
        for (int r = 0; r < 4; ++r) {
            int rl   = wm * 64 + mi * 16 + q * 4 + r;
            int orig = orig_s[rl];
            int tg   = tgt_s[rl];
            float sum = 0.f;
#pragma unroll
            for (int ni = 0; ni < 2; ++ni) {
                int cl = wn * 32 + ni * 16 + s;
                int cg = c0 + cl;
                float logit = acc[mi][ni][r] + bias_s[cl];
                bool valid = (cg < C) && (orig >= 0);
                float e = valid ? __expf(logit) : 0.f;
                sum += e;
                if (valid && (class_base + cg == tg)) capture[orig] = logit;
            }
            sum += __shfl_xor(sum, 1, 64);
            sum += __shfl_xor(sum, 2, 64);
            sum += __shfl_xor(sum, 4, 64);
            sum += __shfl_xor(sum, 8, 64);
            if (s == 0 && orig >= 0) atomicAdd(&sumexp[orig], sum);
        }
    }
}

// ---------------------------------------------------------------------------
// FALLBACK PATH (fp32 staging) -- used if ws too small
// ---------------------------------------------------------------------------
__launch_bounds__(256)
__global__ void gemm_lse_k(const float* __restrict__ input,
                           const float* __restrict__ weight,
                           const float* __restrict__ bias,
                           const int*   __restrict__ target,
                           const int*   __restrict__ rowlist,
                           const int*   __restrict__ cnt_ptr,
                           int fixed_cnt,
                           int class_base, int C,
                           float* __restrict__ sumexp,
                           float* __restrict__ capture)
{
    const int cnt = cnt_ptr ? *cnt_ptr : fixed_cnt;
    const int r0  = blockIdx.x * 128;
    if (r0 >= cnt) return;
    const int c0  = blockIdx.y * 128;

    __shared__ unsigned short As[128 * 40];
    __shared__ unsigned short Bs[128 * 40];
    __shared__ int   orig_s[128];
    __shared__ int   tgt_s[128];
    __shared__ float bias_s[128];

    const int tid = threadIdx.x;
    if (tid < 128) {
        int idx  = r0 + tid;
        int orig = -1;
        if (idx < cnt) orig = rowlist ? rowlist[idx] : idx;
        orig_s[tid] = orig;
        tgt_s[tid]  = (orig >= 0) ? target[orig] : -1;
        int c = c0 + tid;
        bias_s[tid] = (c < C) ? bias[class_base + c] : 0.f;
    }

    const int lane = tid & 63;
    const int wave = tid >> 6;
    const int wm = wave >> 1, wn = wave & 1;
    const int q = lane >> 4, s = lane & 15;

    int aoff[4], boff[4];
#pragma unroll
    for (int i = 0; i < 4; ++i) {
        aoff[i] = (wm * 64 + i * 16 + s) * 40 + q * 8;
        boff[i] = (wn * 64 + i * 16 + s) * 40 + q * 8;
    }

    f32x4 acc[4][4];
#pragma unroll
    for (int mi = 0; mi < 4; ++mi)
#pragma unroll
        for (int ni = 0; ni < 4; ++ni) acc[mi][ni] = (f32x4)0.f;

    for (int k0 = 0; k0 < IN_F; k0 += 32) {
        __syncthreads();
#pragma unroll
        for (int i = 0; i < 2; ++i) {
            int sg  = tid + i * 256;
            int row = sg >> 2;
            int sk  = (sg & 3) << 3;
            {
                int orig = orig_s[row];
                float v[8];
                if (orig >= 0) {
                    const float* p = input + (size_t)orig * IN_F + k0 + sk;
                    f32x4 x0 = *(const f32x4*)p;
                    f32x4 x1 = *(const f32x4*)(p + 4);
                    v[0]=x0[0]; v[1]=x0[1]; v[2]=x0[2]; v[3]=x0[3];
                    v[4]=x1[0]; v[5]=x1[1]; v[6]=x1[2]; v[7]=x1[3];
                } else {
#pragma unroll
                    for (int j = 0; j < 8; ++j) v[j] = 0.f;
                }
                us8 o;
#pragma unroll
                for (int j = 0; j < 8; ++j) o[j] = f2bf(v[j]);
                *(us8*)&As[row * 40 + sk] = o;
            }
            {
                int c = c0 + row;
                float v[8];
                if (c < C) {
                    const float* p = weight + (size_t)(class_base + c) * IN_F + k0 + sk;
                    f32x4 x0 = *(const f32x4*)p;
                    f32x4 x1 = *(const f32x4*)(p + 4);
                    v[0]=x0[0]; v[1]=x0[1]; v[2]=x0[2]; v[3]=x0[3];
                    v[4]=x1[0]; v[5]=x1[1]; v[6]=x1[2]; v[7]=x1[3];
                } else {
#pragma unroll
                    for (int j = 0; j < 8; ++j) v[j] = 0.f;
                }
                us8 o;
#pragma unroll
                for (int j = 0; j < 8; ++j) o[j] = f2bf(v[j]);
                *(us8*)&Bs[row * 40 + sk] = o;
            }
        }
        __syncthreads();

        bf16x8 av[4], bv[4];
#pragma unroll
        for (int i = 0; i < 4; ++i) {
            av[i] = *(const bf16x8*)&As[aoff[i]];
            bv[i] = *(const bf16x8*)&Bs[boff[i]];
        }
#pragma unroll
        for (int mi = 0; mi < 4; ++mi)
#pragma unroll
            for (int ni = 0; ni < 4; ++ni)
                acc[mi][ni] = __builtin_amdgcn_mfma_f32_16x16x32_bf16(
                    av[mi], bv[ni], acc[mi][ni], 0, 0, 0);
    }

#pragma unroll
    for (int mi = 0; mi < 4; ++mi) {
#pragma unroll
        for (int r = 0; r < 4; ++r) {
            int rl   = wm * 64 + mi * 16 + q * 4 + r;
            int orig = orig_s[rl];
            int tg   = tgt_s[rl];
            float sum = 0.f;
#pragma unroll
            for (int ni = 0; ni < 4; ++ni) {
                int cl = wn * 64 + ni * 16 + s;
                int cg = c0 + cl;
                float logit = acc[mi][ni][r] + bias_s[cl];
                bool valid = (cg < C) && (orig >= 0);
                float e = valid ? __expf(logit) : 0.f;
                sum += e;
                if (valid && (class_base + cg == tg)) capture[orig] = logit;
            }
            sum += __shfl_xor(sum, 1, 64);
            sum += __shfl_xor(sum, 2, 64);
            sum += __shfl_xor(sum, 4, 64);
            sum += __shfl_xor(sum, 8, 64);
            if (s == 0 && orig >= 0) atomicAdd(&sumexp[orig], sum);
        }
    }
}

// ---------------------------------------------------------------------------
// Combine: tail-vector logits (2 dots/row, fp32), assemble output, loss accum
// ---------------------------------------------------------------------------
__global__ void combine_k(const float* __restrict__ input,
                          const int*   __restrict__ target,
                          const float* __restrict__ tv,
                          const float* __restrict__ tb,
                          const float* __restrict__ sumexp_head,
                          const float* __restrict__ sumexp_tail,
                          const float* __restrict__ capture,
                          float* __restrict__ out,
                          float* __restrict__ loss_accum)
{
    const int wave = threadIdx.x >> 6, lane = threadIdx.x & 63;
    const int row = blockIdx.x * 4 + wave;
    if (row >= NROWS) return;

    const float* x  = input + (size_t)row * IN_F + lane * 16;
    const float* p0 = tv + lane * 16;
    const float* p1 = tv + IN_F + lane * 16;
    float d0 = 0.f, d1 = 0.f;
#pragma unroll
    for (int i = 0; i < 16; i += 4) {
        f32x4 xv = *(const f32x4*)(x  + i);
        f32x4 a  = *(const f32x4*)(p0 + i);
        f32x4 b  = *(const f32x4*)(p1 + i);
        d0 += xv[0]*a[0] + xv[1]*a[1] + xv[2]*a[2] + xv[3]*a[3];
        d1 += xv[0]*b[0] + xv[1]*b[1] + xv[2]*b[2] + xv[3]*b[3];
    }
#pragma unroll
    for (int m = 32; m; m >>= 1) {
        d0 += __shfl_xor(d0, m, 64);
        d1 += __shfl_xor(d1, m, 64);
    }
    if (lane == 0) {
        float t0 = d0 + tb[0];
        float t1 = d1 + tb[1];
        int tg  = target[row];
        int cid = (tg < C1_LO) ? 0 : ((tg < C1_HI) ? 1 : 2);
        float se_head  = sumexp_head[row] + __expf(t0) + __expf(t1);
        float lse_head = __logf(se_head);
        float head_num = (cid == 0) ? capture[row] : ((cid == 1) ? t0 : t1);
        float o = head_num - lse_head;
        if (cid != 0) o += capture[row] - __logf(sumexp_tail[row]);
        out[row] = o;
        atomicAdd(loss_accum, o);
    }
}

__global__ void finalize_k(const float* __restrict__ loss_accum, float* __restrict__ out) {
    out[NROWS] = -loss_accum[0] * (1.0f / NROWS);
}

// ---------------------------------------------------------------------------
extern "C" void kernel_launch(void* const* d_in, const int* in_sizes, int n_in,
                              void* d_out, int out_size, void* d_ws, size_t ws_size,
                              hipStream_t stream) {
    const float* input  = (const float*)d_in[0];
    const int*   target = (const int*)  d_in[1];
    const float* weight = (const float*)d_in[2];
    const float* bias   = (const float*)d_in[3];
    const float* tv     = (const float*)d_in[4];
    const float* tb     = (const float*)d_in[5];
    float* out = (float*)d_out;
    int*   wsI = (int*)d_ws;
    float* wsF = (float*)d_ws;

    init_ws_k<<<dim3((WS_WORDS + 255) / 256), 256, 0, stream>>>(wsI);
    compact_rows_k<<<dim3(NROWS / 256), 256, 0, stream>>>(target, wsI);

    const bool fast = ws_size >= (size_t)WS_NEEDED;

    if (fast) {
        ushort_t* Wbf = (ushort_t*)((char*)d_ws + WBF_OFF);
        ushort_t* Xbf = (ushort_t*)((char*)d_ws + XBF_OFF);

        const int wchunks = (C2_HI * IN_F) / 8;     // 6,432,896
        const int xchunks = (NROWS * IN_F) / 8;     // 1,048,576
        convert_bf16_k<<<dim3((wchunks + 255) / 256), 256, 0, stream>>>(weight, Wbf, wchunks);
        convert_bf16_k<<<dim3((xchunks + 255) / 256), 256, 0, stream>>>(input, Xbf, xchunks);

        // grid = (row-strips of 128, col-strips of 64); x fastest -> B reuse in L2
        // Head: all rows vs classes [0, 4000)
        gemm_lse_bf16_k<<<dim3(NROWS / 128, (SHORTLIST + 63) / 64), 256, 0, stream>>>(
            Xbf, Wbf, bias, target,
            nullptr, nullptr, NROWS,
            0, SHORTLIST,
            wsF + WS_SEH, wsF + WS_CAP);

        // Tail cluster 1: compacted rows vs classes [4000, 20000)
        gemm_lse_bf16_k<<<dim3(NROWS / 128, (C1_HI - C1_LO + 63) / 64), 256, 0, stream>>>(
            Xbf, Wbf, bias, target,
            wsI + WS_RL1, wsI + WS_CNT1, 0,
            C1_LO, C1_HI - C1_LO,
            wsF + WS_SET, wsF + WS_CAP);

        // Tail cluster 2: compacted rows vs classes [20000, 50257)
        gemm_lse_bf16_k<<<dim3(NROWS / 128, (C2_HI - C1_HI + 63) / 64), 256, 0, stream>>>(
            Xbf, Wbf, bias, target,
            wsI + WS_RL2, wsI + WS_CNT2, 0,
            C1_HI, C2_HI - C1_HI,
            wsF + WS_SET, wsF + WS_CAP);
    } else {
        gemm_lse_k<<<dim3(NROWS / 128, (SHORTLIST + 127) / 128), 256, 0, stream>>>(
            input, weight, bias, target,
            nullptr, nullptr, NROWS,
            0, SHORTLIST,
            wsF + WS_SEH, wsF + WS_CAP);
        gemm_lse_k<<<dim3(NROWS / 128, (C1_HI - C1_LO + 127) / 128), 256, 0, stream>>>(
            input, weight, bias, target,
            wsI + WS_RL1, wsI + WS_CNT1, 0,
            C1_LO, C1_HI - C1_LO,
            wsF + WS_SET, wsF + WS_CAP);
        gemm_lse_k<<<dim3(NROWS / 128, (C2_HI - C1_HI + 127) / 128), 256, 0, stream>>>(
            input, weight, bias, target,
            wsI + WS_RL2, wsI + WS_CNT2, 0,
            C1_HI, C2_HI - C1_HI,
            wsF + WS_SET, wsF + WS_CAP);
    }

    combine_k<<<dim3(NROWS / 4), 256, 0, stream>>>(
        input, target, tv, tb,
        wsF + WS_SEH, wsF + WS_SET, wsF + WS_CAP,
        out, wsF + WS_LOSS);

    finalize_k<<<1, 1, 0, stream>>>(wsF + WS_LOSS, out);
}

// Round 6
// 1439.302 us; speedup vs baseline: 1.0141x; 1.0141x over previous
//
#include <hip/hip_runtime.h>
#include <stddef.h>
#include <stdint.h>

// Problem constants
#define IN_F      1024
#define SHORTLIST 4000
#define C1_LO     4000
#define C1_HI     20000
#define C2_HI     50257
#define NROWS     8192

// Workspace layout (4-byte words) -- bookkeeping region
#define WS_CNT1   0
#define WS_CNT2   1
#define WS_LOSS   2
#define WS_RL1    4
#define WS_RL2    (4 + 8192)
#define WS_SEH    (4 + 2*8192)            // sumexp_head[8192]
#define WS_SET    (WS_SEH + 8192)         // sumexp_tail[8192]
#define WS_CAP    (WS_SET + 8192)         // captured target/gather logit[8192]
#define WS_WORDS  (WS_CAP + 8192)         // ~164 KB

// bf16 scratch region (bytes)
#define WBF_OFF   (262144)                              // 256 KB aligned
#define XBF_OFF   (WBF_OFF + 103219200)                 // padded/aligned
#define XBF_BYTES ((size_t)NROWS * IN_F * 2)            // 16,777,216
#define WS_NEEDED (XBF_OFF + XBF_BYTES)

// Fused-GEMM grid: jobs concatenated, row-strip (of 128) fastest for B L2 reuse.
// Each block covers 4 column-tiles of 128 => 512 classes.
#define GRID_HEAD 512          // 64 rowstrips x 8  cgroups (4000 cls -> 32 strips)
#define GRID_T1   2048         // 64 rowstrips x 32 cgroups (16000 -> 125 strips)
#define GRID_T2   3840         // 64 rowstrips x 60 cgroups (30257 -> 237 strips)
#define GRID_ALL  (GRID_HEAD + GRID_T1 + GRID_T2)

typedef float          f32x4  __attribute__((ext_vector_type(4)));
typedef __bf16         bf16x8 __attribute__((ext_vector_type(8)));
typedef unsigned short us8    __attribute__((ext_vector_type(8)));
typedef unsigned short ushort_t;

__device__ __forceinline__ unsigned short f2bf(float f) {
    unsigned int u = __float_as_uint(f);
    u += 0x7fffu + ((u >> 16) & 1u);   // round-to-nearest-even
    return (unsigned short)(u >> 16);
}

__device__ __forceinline__ void gl_lds16(const void* g, void* l) {
    __builtin_amdgcn_global_load_lds(
        (const __attribute__((address_space(1))) void*)g,
        (__attribute__((address_space(3))) void*)l, 16, 0, 0);
}

// ---------------------------------------------------------------------------
__global__ void init_ws_k(int* __restrict__ ws) {
    int i = blockIdx.x * 256 + threadIdx.x;
    if (i < WS_WORDS) {
        int v = (i >= WS_RL1 && i < WS_RL1 + 2*8192) ? -1 : 0;
        ws[i] = v;
    }
}

__global__ void compact_rows_k(const int* __restrict__ target, int* __restrict__ ws) {
    int row = blockIdx.x * 256 + threadIdx.x;
    if (row >= NROWS) return;
    int tg = target[row];
    if (tg >= C1_LO) {
        if (tg < C1_HI) {
            int p = atomicAdd(&ws[WS_CNT1], 1);
            ws[WS_RL1 + p] = row;
        } else {
            int p = atomicAdd(&ws[WS_CNT2], 1);
            ws[WS_RL2 + p] = row;
        }
    }
}

// ---------------------------------------------------------------------------
// fp32 -> bf16 bulk convert: weight then input in one dispatch
// ---------------------------------------------------------------------------
#define WCHUNKS ((C2_HI * IN_F) / 8)       // 6,432,896
#define XCHUNKS ((NROWS * IN_F) / 8)       // 1,048,576
__global__ void convert_bf16_k(const float* __restrict__ w_src,
                               ushort_t* __restrict__ w_dst,
                               const float* __restrict__ x_src,
                               ushort_t* __restrict__ x_dst) {
    int i = blockIdx.x * 256 + threadIdx.x;
    const float* p;
    ushort_t* d;
    if (i < WCHUNKS) { p = w_src + (size_t)i * 8; d = w_dst + (size_t)i * 8; }
    else {
        int j = i - WCHUNKS;
        if (j >= XCHUNKS) return;
        p = x_src + (size_t)j * 8; d = x_dst + (size_t)j * 8;
    }
    f32x4 x0 = *(const f32x4*)p;
    f32x4 x1 = *(const f32x4*)(p + 4);
    us8 o;
    o[0] = f2bf(x0[0]); o[1] = f2bf(x0[1]); o[2] = f2bf(x0[2]); o[3] = f2bf(x0[3]);
    o[4] = f2bf(x1[0]); o[5] = f2bf(x1[1]); o[6] = f2bf(x1[2]); o[7] = f2bf(x1[3]);
    *(us8*)d = o;
}

// ---------------------------------------------------------------------------
// FUSED bf16 GEMM + exp-sum + target capture, all 3 cluster jobs in one grid.
// 128x128 tile, BK=64, gl_lds(16B) staging, XOR-swizzled LDS (conflict-free).
// Each block processes 4 consecutive column-tiles (512 classes), accumulating
// per-row exp-sums in LDS across tiles and merging wave halves at the end:
// 128 global atomics per block (16x fewer than r5 -> kills the HBM RMW storm).
// ---------------------------------------------------------------------------
__launch_bounds__(256)
__global__ void gemm_lse_fused_k(const ushort_t* __restrict__ Xbf,  // [NROWS][IN_F]
                                 const ushort_t* __restrict__ Wbf,  // [C2_HI][IN_F]
                                 const float* __restrict__ bias,
                                 const int*   __restrict__ target,
                                 int*   __restrict__ wsI,
                                 float* __restrict__ wsF)
{
    // ---- job decode (row-strip fastest within each job)
    const int bid = blockIdx.x;
    int rs, cg, cbase, C, cnt;
    const int* rowlist;           // null => identity
    float* sumexp;
    if (bid < GRID_HEAD) {
        rs = bid & 63; cg = bid >> 6;
        cbase = 0; C = SHORTLIST; rowlist = nullptr; cnt = NROWS;
        sumexp = wsF + WS_SEH;
    } else if (bid < GRID_HEAD + GRID_T1) {
        int b = bid - GRID_HEAD;
        rs = b & 63; cg = b >> 6;
        cbase = C1_LO; C = C1_HI - C1_LO; rowlist = wsI + WS_RL1; cnt = wsI[WS_CNT1];
        sumexp = wsF + WS_SET;
    } else {
        int b = bid - (GRID_HEAD + GRID_T1);
        rs = b & 63; cg = b >> 6;
        cbase = C1_HI; C = C2_HI - C1_HI; rowlist = wsI + WS_RL2; cnt = wsI[WS_CNT2];
        sumexp = wsF + WS_SET;
    }
    const int r0 = rs * 128;
    if (r0 >= cnt) return;
    float* capture = wsF + WS_CAP;

    __shared__ ushort_t As[128 * 64];   // 16 KB
    __shared__ ushort_t Bs[128 * 64];   // 16 KB
    __shared__ int   orig_s[128];
    __shared__ int   tgt_s[128];
    __shared__ float part[256];         // [wn][row] exp-sum accum across ctiles

    const int tid = threadIdx.x;
    part[tid] = 0.f;
    if (tid < 128) {
        int idx  = r0 + tid;
        int orig = (idx < cnt) ? (rowlist ? rowlist[idx] : idx) : -1;
        orig_s[tid] = orig;
        tgt_s[tid]  = (orig >= 0) ? target[orig] : -1;
    }
    __syncthreads();

    const int lane = tid & 63;
    const int wave = tid >> 6;
    const int wm = wave >> 1, wn = wave & 1;
    const int q = lane >> 4, s = lane & 15;

    // ---- staging setup: wave handles insts t = wave*4+i, rows t*8..t*8+7
    // lane l -> row t*8 + (l>>3), LDS slot l&7; data chunk = (l&7)^(l>>3)
    const int lrow  = lane >> 3;
    const int chunk = (lane & 7) ^ lrow;
    const ushort_t* aptr[4];
    ushort_t* alds[4];
    ushort_t* blds[4];
    int brow[4];
#pragma unroll
    for (int i = 0; i < 4; ++i) {
        int t  = wave * 4 + i;
        int rt = t * 8 + lrow;
        int orig = orig_s[rt]; if (orig < 0) orig = 0;          // safe addr; masked later
        aptr[i] = Xbf + (size_t)orig * IN_F + chunk * 8;
        alds[i] = &As[t * 512];
        blds[i] = &Bs[t * 512];
        brow[i] = rt;
    }

    // ---- fragment read offsets (ushort units)
    int aoff[4], boff[4];
#pragma unroll
    for (int i = 0; i < 4; ++i) {
        aoff[i] = (wm * 64 + i * 16 + s) * 64;
        boff[i] = (wn * 64 + i * 16 + s) * 64;
    }
    const int slot0 = (q ^ (s & 7)) * 8;        // k-chunk q   for ks=0
    const int slot1 = slot0 ^ (4 * 8);          // k-chunk q+4 for ks=1

    // ---- loop over 4 column-tiles
    for (int ct = 0; ct < 4; ++ct) {
        const int c0 = (cg * 4 + ct) * 128;
        if (c0 >= C) break;                     // block-uniform

        const ushort_t* bptr[4];
#pragma unroll
        for (int i = 0; i < 4; ++i) {
            int c = c0 + brow[i]; if (c >= C) c = C - 1;    // clamp; masked later
            bptr[i] = Wbf + (size_t)(cbase + c) * IN_F + chunk * 8;
        }

        f32x4 acc[4][4];
#pragma unroll
        for (int mi = 0; mi < 4; ++mi)
#pragma unroll
            for (int ni = 0; ni < 4; ++ni) acc[mi][ni] = (f32x4)0.f;

        for (int k0 = 0; k0 < IN_F; k0 += 64) {
            __syncthreads();   // previous readers (K-iter or epilogue) done
#pragma unroll
            for (int i = 0; i < 4; ++i) {
                gl_lds16(aptr[i] + k0, alds[i]);
                gl_lds16(bptr[i] + k0, blds[i]);
            }
            __syncthreads();   // DMA drained

#pragma unroll
            for (int ks = 0; ks < 2; ++ks) {
                const int sl = ks ? slot1 : slot0;
                bf16x8 av[4], bv[4];
#pragma unroll
                for (int i = 0; i < 4; ++i) {
                    av[i] = *(const bf16x8*)&As[aoff[i] + sl];
                    bv[i] = *(const bf16x8*)&Bs[boff[i] + sl];
                }
#pragma unroll
                for (int mi = 0; mi < 4; ++mi)
#pragma unroll
                    for (int ni = 0; ni < 4; ++ni)
                        acc[mi][ni] = __builtin_amdgcn_mfma_f32_16x16x32_bf16(
                            av[mi], bv[ni], acc[mi][ni], 0, 0, 0);
            }
        }

        // ---- per-ctile epilogue: C/D layout col = lane&15 (=s), row = q*4+reg
        float bias_v[4];
#pragma unroll
        for (int ni = 0; ni < 4; ++ni) {
            int cgl = c0 + wn * 64 + ni * 16 + s;
            bias_v[ni] = (cgl < C) ? bias[cbase + cgl] : 0.f;
        }
#pragma unroll
        for (int mi = 0; mi < 4; ++mi) {
#pragma unroll
            for (int r = 0; r < 4; ++r) {
                int rl   = wm * 64 + mi * 16 + q * 4 + r;
                int orig = orig_s[rl];
                int tg   = tgt_s[rl];
                float sum = 0.f;
#pragma unroll
                for (int ni = 0; ni < 4; ++ni) {
                    int cgl = c0 + wn * 64 + ni * 16 + s;
                    float logit = acc[mi][ni][r] + bias_v[ni];
                    bool valid = (cgl < C) && (orig >= 0);
                    float e = valid ? __expf(logit) : 0.f;
                    sum += e;
                    if (valid && (cbase + cgl == tg)) capture[orig] = logit;
                }
                sum += __shfl_xor(sum, 1, 64);
                sum += __shfl_xor(sum, 2, 64);
                sum += __shfl_xor(sum, 4, 64);
                sum += __shfl_xor(sum, 8, 64);
                if (s == 0 && orig >= 0) part[wn * 128 + rl] += sum;  // lane-owned slot
            }
        }
    }

    // ---- merge wave halves, one atomic per row per block
    __syncthreads();
    if (tid < 128) {
        int orig = orig_s[tid];
        if (orig >= 0) {
            float tot = part[tid] + part[128 + tid];
            atomicAdd(&sumexp[orig], tot);
        }
    }
}

// ---------------------------------------------------------------------------
// FALLBACK PATH (fp32 staging) -- used if ws too small
// ---------------------------------------------------------------------------
__launch_bounds__(256)
__global__ void gemm_lse_k(const float* __restrict__ input,
                           const float* __restrict__ weight,
                           const float* __restrict__ bias,
                           const int*   __restrict__ target,
                           const int*   __restrict__ rowlist,
                           const int*   __restrict__ cnt_ptr,
                           int fixed_cnt,
                           int class_base, int C,
                           float* __restrict__ sumexp,
                           float* __restrict__ capture)
{
    const int cnt = cnt_ptr ? *cnt_ptr : fixed_cnt;
    const int r0  = blockIdx.x * 128;
    if (r0 >= cnt) return;
    const int c0  = blockIdx.y * 128;

    __shared__ unsigned short As[128 * 40];
    __shared__ unsigned short Bs[128 * 40];
    __shared__ int   orig_s[128];
    __shared__ int   tgt_s[128];
    __shared__ float bias_s[128];

    const int tid = threadIdx.x;
    if (tid < 128) {
        int idx  = r0 + tid;
        int orig = -1;
        if (idx < cnt) orig = rowlist ? rowlist[idx] : idx;
        orig_s[tid] = orig;
        tgt_s[tid]  = (orig >= 0) ? target[orig] : -1;
        int c = c0 + tid;
        bias_s[tid] = (c < C) ? bias[class_base + c] : 0.f;
    }

    const int lane = tid & 63;
    const int wave = tid >> 6;
    const int wm = wave >> 1, wn = wave & 1;
    const int q = lane >> 4, s = lane & 15;

    int aoff[4], boff[4];
#pragma unroll
    for (int i = 0; i < 4; ++i) {
        aoff[i] = (wm * 64 + i * 16 + s) * 40 + q * 8;
        boff[i] = (wn * 64 + i * 16 + s) * 40 + q * 8;
    }

    f32x4 acc[4][4];
#pragma unroll
    for (int mi = 0; mi < 4; ++mi)
#pragma unroll
        for (int ni = 0; ni < 4; ++ni) acc[mi][ni] = (f32x4)0.f;

    for (int k0 = 0; k0 < IN_F; k0 += 32) {
        __syncthreads();
#pragma unroll
        for (int i = 0; i < 2; ++i) {
            int sg  = tid + i * 256;
            int row = sg >> 2;
            int sk  = (sg & 3) << 3;
            {
                int orig = orig_s[row];
                float v[8];
                if (orig >= 0) {
                    const float* p = input + (size_t)orig * IN_F + k0 + sk;
                    f32x4 x0 = *(const f32x4*)p;
                    f32x4 x1 = *(const f32x4*)(p + 4);
                    v[0]=x0[0]; v[1]=x0[1]; v[2]=x0[2]; v[3]=x0[3];
                    v[4]=x1[0]; v[5]=x1[1]; v[6]=x1[2]; v[7]=x1[3];
                } else {
#pragma unroll
                    for (int j = 0; j < 8; ++j) v[j] = 0.f;
                }
                us8 o;
#pragma unroll
                for (int j = 0; j < 8; ++j) o[j] = f2bf(v[j]);
                *(us8*)&As[row * 40 + sk] = o;
            }
            {
                int c = c0 + row;
                float v[8];
                if (c < C) {
                    const float* p = weight + (size_t)(class_base + c) * IN_F + k0 + sk;
                    f32x4 x0 = *(const f32x4*)p;
                    f32x4 x1 = *(const f32x4*)(p + 4);
                    v[0]=x0[0]; v[1]=x0[1]; v[2]=x0[2]; v[3]=x0[3];
                    v[4]=x1[0]; v[5]=x1[1]; v[6]=x1[2]; v[7]=x1[3];
                } else {
#pragma unroll
                    for (int j = 0; j < 8; ++j) v[j] = 0.f;
                }
                us8 o;
#pragma unroll
                for (int j = 0; j < 8; ++j) o[j] = f2bf(v[j]);
                *(us8*)&Bs[row * 40 + sk] = o;
            }
        }
        __syncthreads();

        bf16x8 av[4], bv[4];
#pragma unroll
        for (int i = 0; i < 4; ++i) {
            av[i] = *(const bf16x8*)&As[aoff[i]];
            bv[i] = *(const bf16x8*)&Bs[boff[i]];
        }
#pragma unroll
        for (int mi = 0; mi < 4; ++mi)
#pragma unroll
            for (int ni = 0; ni < 4; ++ni)
                acc[mi][ni] = __builtin_amdgcn_mfma_f32_16x16x32_bf16(
                    av[mi], bv[ni], acc[mi][ni], 0, 0, 0);
    }

#pragma unroll
    for (int mi = 0; mi < 4; ++mi) {
#pragma unroll
        for (int r = 0; r < 4; ++r) {
            int rl   = wm * 64 + mi * 16 + q * 4 + r;
            int orig = orig_s[rl];
            int tg   = tgt_s[rl];
            float sum = 0.f;
#pragma unroll
            for (int ni = 0; ni < 4; ++ni) {
                int cl = wn * 64 + ni * 16 + s;
                int cg = c0 + cl;
                float logit = acc[mi][ni][r] + bias_s[cl];
                bool valid = (cg < C) && (orig >= 0);
                float e = valid ? __expf(logit) : 0.f;
                sum += e;
                if (valid && (class_base + cg == tg)) capture[orig] = logit;
            }
            sum += __shfl_xor(sum, 1, 64);
            sum += __shfl_xor(sum, 2, 64);
            sum += __shfl_xor(sum, 4, 64);
            sum += __shfl_xor(sum, 8, 64);
            if (s == 0 && orig >= 0) atomicAdd(&sumexp[orig], sum);
        }
    }
}

// ---------------------------------------------------------------------------
// Combine: tail-vector logits (2 dots/row, fp32), assemble output, loss accum
// ---------------------------------------------------------------------------
__global__ void combine_k(const float* __restrict__ input,
                          const int*   __restrict__ target,
                          const float* __restrict__ tv,
                          const float* __restrict__ tb,
                          const float* __restrict__ sumexp_head,
                          const float* __restrict__ sumexp_tail,
                          const float* __restrict__ capture,
                          float* __restrict__ out,
                          float* __restrict__ loss_accum)
{
    const int wave = threadIdx.x >> 6, lane = threadIdx.x & 63;
    const int row = blockIdx.x * 4 + wave;
    if (row >= NROWS) return;

    const float* x  = input + (size_t)row * IN_F + lane * 16;
    const float* p0 = tv + lane * 16;
    const float* p1 = tv + IN_F + lane * 16;
    float d0 = 0.f, d1 = 0.f;
#pragma unroll
    for (int i = 0; i < 16; i += 4) {
        f32x4 xv = *(const f32x4*)(x  + i);
        f32x4 a  = *(const f32x4*)(p0 + i);
        f32x4 b  = *(const f32x4*)(p1 + i);
        d0 += xv[0]*a[0] + xv[1]*a[1] + xv[2]*a[2] + xv[3]*a[3];
        d1 += xv[0]*b[0] + xv[1]*b[1] + xv[2]*b[2] + xv[3]*b[3];
    }
#pragma unroll
    for (int m = 32; m; m >>= 1) {
        d0 += __shfl_xor(d0, m, 64);
        d1 += __shfl_xor(d1, m, 64);
    }
    if (lane == 0) {
        float t0 = d0 + tb[0];
        float t1 = d1 + tb[1];
        int tg  = target[row];
        int cid = (tg < C1_LO) ? 0 : ((tg < C1_HI) ? 1 : 2);
        float se_head  = sumexp_head[row] + __expf(t0) + __expf(t1);
        float lse_head = __logf(se_head);
        float head_num = (cid == 0) ? capture[row] : ((cid == 1) ? t0 : t1);
        float o = head_num - lse_head;
        if (cid != 0) o += capture[row] - __logf(sumexp_tail[row]);
        out[row] = o;
        atomicAdd(loss_accum, o);
    }
}

__global__ void finalize_k(const float* __restrict__ loss_accum, float* __restrict__ out) {
    out[NROWS] = -loss_accum[0] * (1.0f / NROWS);
}

// ---------------------------------------------------------------------------
extern "C" void kernel_launch(void* const* d_in, const int* in_sizes, int n_in,
                              void* d_out, int out_size, void* d_ws, size_t ws_size,
                              hipStream_t stream) {
    const float* input  = (const float*)d_in[0];
    const int*   target = (const int*)  d_in[1];
    const float* weight = (const float*)d_in[2];
    const float* bias   = (const float*)d_in[3];
    const float* tv     = (const float*)d_in[4];
    const float* tb     = (const float*)d_in[5];
    float* out = (float*)d_out;
    int*   wsI = (int*)d_ws;
    float* wsF = (float*)d_ws;

    init_ws_k<<<dim3((WS_WORDS + 255) / 256), 256, 0, stream>>>(wsI);
    compact_rows_k<<<dim3(NROWS / 256), 256, 0, stream>>>(target, wsI);

    const bool fast = ws_size >= (size_t)WS_NEEDED;

    if (fast) {
        ushort_t* Wbf = (ushort_t*)((char*)d_ws + WBF_OFF);
        ushort_t* Xbf = (ushort_t*)((char*)d_ws + XBF_OFF);

        convert_bf16_k<<<dim3((WCHUNKS + XCHUNKS + 255) / 256), 256, 0, stream>>>(
            weight, Wbf, input, Xbf);

        gemm_lse_fused_k<<<dim3(GRID_ALL), 256, 0, stream>>>(
            Xbf, Wbf, bias, target, wsI, wsF);
    } else {
        gemm_lse_k<<<dim3(NROWS / 128, (SHORTLIST + 127) / 128), 256, 0, stream>>>(
            input, weight, bias, target,
            nullptr, nullptr, NROWS,
            0, SHORTLIST,
            wsF + WS_SEH, wsF + WS_CAP);
        gemm_lse_k<<<dim3(NROWS / 128, (C1_HI - C1_LO + 127) / 128), 256, 0, stream>>>(
            input, weight, bias, target,
            wsI + WS_RL1, wsI + WS_CNT1, 0,
            C1_LO, C1_HI - C1_LO,
            wsF + WS_SET, wsF + WS_CAP);
        gemm_lse_k<<<dim3(NROWS / 128, (C2_HI - C1_HI + 127) / 128), 256, 0, stream>>>(
            input, weight, bias, target,
            wsI + WS_RL2, wsI + WS_CNT2, 0,
            C1_HI, C2_HI - C1_HI,
            wsF + WS_SET, wsF + WS_CAP);
    }

    combine_k<<<dim3(NROWS / 4), 256, 0, stream>>>(
        input, target, tv, tb,
        wsF + WS_SEH, wsF + WS_SET, wsF + WS_CAP,
        out, wsF + WS_LOSS);

    finalize_k<<<1, 1, 0, stream>>>(wsF + WS_LOSS, out);
}